// Round 1
// 109.620 us; speedup vs baseline: 1.0003x; 1.0003x over previous
//
#include <hip/hip_runtime.h>
#include <hip/hip_fp16.h>
#include <math.h>

#define BB 4
#define CC 64
#define HH 128
#define WW 128
#define OO 64
#define HWW (HH * WW)

typedef _Float16 f16x8 __attribute__((ext_vector_type(8)));
typedef float f32x4 __attribute__((ext_vector_type(4)));

// ws byte offsets (single-f16 weight fragments, ~111 KB)
#define WHF_OFF  0          // main W f16 frags: 18*4*64*8 halfs = 73728 B
#define WOMH_OFF 73728      // om W f16 frags: 18*2*64*8 halfs = 36864 B

__device__ inline __half2 u2h(unsigned u) {
    union { unsigned u; __half2 h; } c; c.u = u; return c.h;
}
__device__ inline unsigned h2u(__half2 h) {
    union { __half2 h; unsigned u; } c; c.h = h; return c.u;
}

// ---------------------------------------------------------------------------
// prep: weights -> single-f16 (RNE) A-fragments.
// chunk ch = half*9 + tap covers channels [half*32, half*32+32) of tap.
// A-frag: lane l holds W[o = og*16 + (l&15)][k = (l>>4)*8 + j].
__global__ void prep_kernel(const float* __restrict__ weight,     // (O,C,3,3)
                            const float* __restrict__ om_weight,  // (27,C,3,3)
                            unsigned short* __restrict__ whf,
                            unsigned short* __restrict__ womh)
{
    int d = blockIdx.x * 256 + threadIdx.x;
    if (d < 18 * 4 * 64 * 8) {
        int j  = d & 7;
        int l  = (d >> 3) & 63;
        int og = (d >> 9) & 3;
        int ch = d >> 11;
        int o  = og * 16 + (l & 15);
        int kk = (l >> 4) * 8 + j;
        int c  = (ch / 9) * 32 + kk;
        int tap = ch % 9;
        float w = weight[(o * CC + c) * 9 + tap];
        whf[d] = __half_as_ushort(__float2half_rn(w));
    }
    int d2 = d - 18 * 4 * 64 * 8;
    if (d2 >= 0 && d2 < 18 * 2 * 64 * 8) {
        int j  = d2 & 7;
        int l  = (d2 >> 3) & 63;
        int og = (d2 >> 9) & 1;
        int ch = d2 >> 10;
        int o  = og * 16 + (l & 15);
        int kk = (l >> 4) * 8 + j;
        int c  = (ch / 9) * 32 + kk;
        int tap = ch % 9;
        float w = (o < 27) ? om_weight[(o * CC + c) * 9 + tap] : 0.f;
        womh[d2] = __half_as_ushort(__float2half_rn(w));
    }
}

// ---------------------------------------------------------------------------
// Fused kernel: 32-pixel tiles, 256 threads = 4 waves, 4 blocks/CU.
// R1: barrier-free main loop. Wave split by (K-chunk kc, N-subtile s) instead
// of (og-pair, s): lane l computes exactly the B-fragment it consumes
// (payload pixel = s*16+(l&15), octet = kc*4+(l>>4) matches 16x16x32 B
// layout), so the vex exchange + 9 per-tap barriers are removed entirely.
// Each wave accumulates all 4 og-groups over its half of C (16 f32 acc);
// the two K-halves are summed once at the end via an 8KB LDS reduction +
// ONE barrier. Barriers: 12 -> 4.
__global__ void __launch_bounds__(256, 4)
fused_kernel(const float* __restrict__ x,     // (B,C,H,W)
             const unsigned short* __restrict__ whf,
             const unsigned short* __restrict__ womh,
             const float* __restrict__ bias,
             const float* __restrict__ om_bias,
             float* __restrict__ out)         // (B,O,H,W)
{
    __shared__ __align__(16) uint4 Xw[8 * 180];    // [oct][pos] 23,040 B
    __shared__ __align__(16) uint4 swth4[288];     // packed f16x2 weights 4,608 B
    __shared__ int sidx[288];                      // 1,152 B
    __shared__ __align__(16) f32x4 red[2 * 4 * 64];// K-half reduction 8,192 B
                                                   // (unions omL)  -> 36,992 B total

    int t    = threadIdx.x;
    int lane = t & 63;
    int wv   = t >> 6;

    int bid = blockIdx.x;           // b*512 + ho*4 + q
    int b   = bid >> 9;
    int r   = bid & 511;
    int ho  = r >> 2;
    int w0  = (r & 3) << 5;

    // ---------------- stage: all 64 ch -> LDS packed f16 octets ------------
    {
        const float* xb = x + (size_t)b * CC * HWW;
#pragma unroll 1
        for (int i = t; i < 8 * 180; i += 256) {
            int cg  = i / 180;
            int pos = i - cg * 180;
            int rr  = pos / 36;
            int cc2 = pos - rr * 36;
            int gy = ho - 2 + rr, gx = w0 - 2 + cc2;
            bool ok = (gy >= 0) & (gy < HH) & (gx >= 0) & (gx < WW);
            int gi = ok ? gy * WW + gx : 0;
            const float* xc = xb + (size_t)cg * 8 * HWW + gi;
            float v0 = xc[0],       v1 = xc[HWW],     v2 = xc[2 * HWW], v3 = xc[3 * HWW];
            float v4 = xc[4 * HWW], v5 = xc[5 * HWW], v6 = xc[6 * HWW], v7 = xc[7 * HWW];
            if (!ok) { v0=0.f; v1=0.f; v2=0.f; v3=0.f; v4=0.f; v5=0.f; v6=0.f; v7=0.f; }
            uint4 p;
            p.x = h2u(__floats2half2_rn(v0, v1));
            p.y = h2u(__floats2half2_rn(v2, v3));
            p.z = h2u(__floats2half2_rn(v4, v5));
            p.w = h2u(__floats2half2_rn(v6, v7));
            Xw[cg * 180 + pos] = p;
        }
    }
    __syncthreads();

    // ---------------- om conv: B = one b128 from window, 1 MFMA/chunk ------
    f32x4 accom = (f32x4){0.f, 0.f, 0.f, 0.f};
    {
        int og = wv & 1;
        int s  = wv >> 1;
        int pix_s = s * 16 + (lane & 15);
        int oct   = lane >> 4;          // k-octet 0..3 within chunk
#pragma unroll 1
        for (int ch = 0; ch < 18; ch++) {
            int half = ch / 9;
            int tap  = ch - half * 9;
            int ky = tap / 3, kx = tap - ky * 3;
            int pos = (ky + 1) * 36 + pix_s + kx + 1;
            union { f16x8 v; uint4 u; } B;
            B.u = Xw[(half * 4 + oct) * 180 + pos];
            const f16x8 a0 = *(const f16x8*)&womh[((size_t)(ch * 2 + og) * 64 + lane) * 8];
            accom = __builtin_amdgcn_mfma_f32_16x16x32_f16(a0, B.v, accom, 0, 0, 0);
        }
    }

    // om epilogue -> omL (union with red region; red unused until main-loop end)
    float* omL = (float*)&red[0];   // 27*32 floats = 3,456 B < 8,192 B
    {
        int og = wv & 1, s = wv >> 1;
#pragma unroll
        for (int rg = 0; rg < 4; rg++) {
            int m = og * 16 + (lane >> 4) * 4 + rg;
            if (m < 27) {
                int pp = s * 16 + (lane & 15);
                float v = accom[rg] + om_bias[m];
                if (m >= 18) v = 1.f / (1.f + expf(-v));
                omL[m * 32 + pp] = v;
            }
        }
    }
    __syncthreads();

    // phase B: sampling params per (tap, pixel) -> packed f16x2 weights
#pragma unroll 1
    for (int it = t; it < 288; it += 256) {
        int k  = it >> 5;
        int pp = it & 31;
        float oy = omL[k * 32 + pp];
        float ox = omL[(9 + k) * 32 + pp];
        float mm = omL[(18 + k) * 32 + pp];
        int ky = k / 3, kx = k - ky * 3;
        float py = oy + (float)(ho + ky - 1);
        float px = ox + (float)(w0 + pp + kx - 1);
        float fy = floorf(py), fx = floorf(px);
        float ly = py - fy, lx = px - fx;
        int y0 = (int)fy, x0 = (int)fx;
        bool vy0 = (y0 >= 0) & (y0 < HH);
        bool vy1 = (y0 + 1 >= 0) & (y0 + 1 < HH);
        bool vx0 = (x0 >= 0) & (x0 < WW);
        bool vx1 = (x0 + 1 >= 0) & (x0 + 1 < WW);
        float w00 = (vy0 & vx0) ? (1.f - ly) * (1.f - lx) * mm : 0.f;
        float w01 = (vy0 & vx1) ? (1.f - ly) * lx * mm : 0.f;
        float w10 = (vy1 & vx0) ? ly * (1.f - lx) * mm : 0.f;
        float w11 = (vy1 & vx1) ? ly * lx * mm : 0.f;
        uint4 wp;
        wp.x = h2u(__float2half2_rn(w00));
        wp.y = h2u(__float2half2_rn(w01));
        wp.z = h2u(__float2half2_rn(w10));
        wp.w = h2u(__float2half2_rn(w11));
        swth4[it] = wp;
        bool inw = (y0 >= ho - 2) & (y0 <= ho + 1) & (x0 >= w0 - 2) & (x0 <= w0 + 32);
        int y0c = min(max(y0, -8), 135);
        int x0c = min(max(x0, -8), 135);
        sidx[it] = ((y0c + 16) << 16) | ((x0c + 16) & 0xFFFF)
                 | (inw ? 0 : (int)0x80000000);
    }
    __syncthreads();

    // ---------------- main conv: barrier-free, wave = (K-chunk, subtile) ---
    int kc    = wv & 1;             // K-chunk: channels [kc*32, kc*32+32)
    int s2    = wv >> 1;            // N-subtile: pixels [s2*16, s2*16+16)
    int pixl  = lane & 15;
    int oct   = lane >> 4;
    int cg    = kc * 4 + oct;       // this lane's channel octet
    int pix32 = s2 * 16 + pixl;     // this lane's pixel in the 32-tile

    f32x4 acc[4];                   // acc[og] = outputs og*16..+16, half-K
    acc[0] = (f32x4){0.f, 0.f, 0.f, 0.f};
    acc[1] = (f32x4){0.f, 0.f, 0.f, 0.f};
    acc[2] = (f32x4){0.f, 0.f, 0.f, 0.f};
    acc[3] = (f32x4){0.f, 0.f, 0.f, 0.f};

    const uint4* Xplane = &Xw[cg * 180];
    // A-frag base for this wave's K-chunk: chunk ch = kc*9 + tap
    const unsigned short* wb = whf + ((size_t)(kc * 36) * 64 + lane) * 8;

#pragma unroll 1
    for (int tap = 0; tap < 9; tap++) {
        int item = tap * 32 + pix32;
        uint4 wp = swth4[item];
        int sv = sidx[item];
        int y0 = ((sv >> 16) & 0x7FFF) - 16;
        int x0 = (sv & 0xFFFF) - 16;
        // A frags: all 4 og-groups for this K-chunk (issued early, L2-hot)
        const f16x8 a0 = *(const f16x8*)&wb[(size_t)(tap * 4 + 0) * 512];
        const f16x8 a1 = *(const f16x8*)&wb[(size_t)(tap * 4 + 1) * 512];
        const f16x8 a2 = *(const f16x8*)&wb[(size_t)(tap * 4 + 2) * 512];
        const f16x8 a3 = *(const f16x8*)&wb[(size_t)(tap * 4 + 3) * 512];

        uint4 payload;
        if (sv >= 0) {
            int o00 = (y0 - ho + 2) * 36 + (x0 - w0 + 2);
            uint4 c00 = Xplane[o00];
            uint4 c01 = Xplane[o00 + 1];
            uint4 c10 = Xplane[o00 + 36];
            uint4 c11 = Xplane[o00 + 37];
            __half2 w00 = u2h(wp.x), w01 = u2h(wp.y);
            __half2 w10 = u2h(wp.z), w11 = u2h(wp.w);
            __half2 vA = __hmul2(w00, u2h(c00.x));
            vA = __hfma2(w01, u2h(c01.x), vA);
            vA = __hfma2(w10, u2h(c10.x), vA);
            vA = __hfma2(w11, u2h(c11.x), vA);
            __half2 vB = __hmul2(w00, u2h(c00.y));
            vB = __hfma2(w01, u2h(c01.y), vB);
            vB = __hfma2(w10, u2h(c10.y), vB);
            vB = __hfma2(w11, u2h(c11.y), vB);
            __half2 vC = __hmul2(w00, u2h(c00.z));
            vC = __hfma2(w01, u2h(c01.z), vC);
            vC = __hfma2(w10, u2h(c10.z), vC);
            vC = __hfma2(w11, u2h(c11.z), vC);
            __half2 vD = __hmul2(w00, u2h(c00.w));
            vD = __hfma2(w01, u2h(c01.w), vD);
            vD = __hfma2(w10, u2h(c10.w), vD);
            vD = __hfma2(w11, u2h(c11.w), vD);
            payload.x = h2u(vA); payload.y = h2u(vB);
            payload.z = h2u(vC); payload.w = h2u(vD);
        } else {
            // rare escape: clamped global gather in f32 (8 channels)
            const float* xg = x + ((size_t)(b * CC + cg * 8)) * HWW;
            float w00f = __low2float(u2h(wp.x)), w01f = __low2float(u2h(wp.y));
            float w10f = __low2float(u2h(wp.z)), w11f = __low2float(u2h(wp.w));
            int cy0 = min(max(y0, 0), HH - 1), cy1 = min(max(y0 + 1, 0), HH - 1);
            int cx0 = min(max(x0, 0), WW - 1), cx1 = min(max(x0 + 1, 0), WW - 1);
            int i00 = cy0 * WW + cx0, i01 = cy0 * WW + cx1;
            int i10 = cy1 * WW + cx0, i11 = cy1 * WW + cx1;
            float vv[8];
#pragma unroll
            for (int j = 0; j < 8; j++) {
                const float* xc = xg + (size_t)j * HWW;
                vv[j] = w00f * xc[i00] + w01f * xc[i01]
                      + w10f * xc[i10] + w11f * xc[i11];
            }
            payload.x = h2u(__floats2half2_rn(vv[0], vv[1]));
            payload.y = h2u(__floats2half2_rn(vv[2], vv[3]));
            payload.z = h2u(__floats2half2_rn(vv[4], vv[5]));
            payload.w = h2u(__floats2half2_rn(vv[6], vv[7]));
        }
        // lane's payload IS its B-fragment: no exchange, no barrier
        union { f16x8 v; uint4 u; } Bf;
        Bf.u = payload;
        acc[0] = __builtin_amdgcn_mfma_f32_16x16x32_f16(a0, Bf.v, acc[0], 0, 0, 0);
        acc[1] = __builtin_amdgcn_mfma_f32_16x16x32_f16(a1, Bf.v, acc[1], 0, 0, 0);
        acc[2] = __builtin_amdgcn_mfma_f32_16x16x32_f16(a2, Bf.v, acc[2], 0, 0, 0);
        acc[3] = __builtin_amdgcn_mfma_f32_16x16x32_f16(a3, Bf.v, acc[3], 0, 0, 0);
    }

    // K-half reduction: kc=1 waves dump, one barrier, kc=0 waves add+store
    if (kc == 1) {
#pragma unroll
        for (int og = 0; og < 4; og++)
            red[(s2 * 4 + og) * 64 + lane] = acc[og];
    }
    __syncthreads();
    if (kc == 0) {
        int prow = ho * WW + w0;
#pragma unroll
        for (int og = 0; og < 4; og++) {
            f32x4 v = acc[og] + red[(s2 * 4 + og) * 64 + lane];
#pragma unroll
            for (int rg = 0; rg < 4; rg++) {
                int o = og * 16 + (lane >> 4) * 4 + rg;
                out[((size_t)(b * OO + o)) * HWW + prow + pix32] = v[rg] + bias[o];
            }
        }
    }
}

// ---------------------------------------------------------------------------
extern "C" void kernel_launch(void* const* d_in, const int* in_sizes, int n_in,
                              void* d_out, int out_size, void* d_ws, size_t ws_size,
                              hipStream_t stream)
{
    (void)in_sizes; (void)n_in; (void)out_size; (void)ws_size;
    const float* x      = (const float*)d_in[0];
    const float* weight = (const float*)d_in[1];
    const float* bias   = (const float*)d_in[2];
    const float* om_w   = (const float*)d_in[3];
    const float* om_b   = (const float*)d_in[4];
    float* out = (float*)d_out;
    char*  ws  = (char*)d_ws;

    unsigned short* whf  = (unsigned short*)(ws + WHF_OFF);
    unsigned short* womh = (unsigned short*)(ws + WOMH_OFF);

    int prep_n = 18 * 4 * 64 * 8 + 18 * 2 * 64 * 8;  // 55296
    prep_kernel<<<(prep_n + 255) / 256, 256, 0, stream>>>(weight, om_w, whf, womh);

    int nblk = BB * HH * (WW / 32);  // 2048
    fused_kernel<<<nblk, 256, 0, stream>>>(x, whf, womh, bias, om_b, out);
}